// Round 1
// baseline (90.797 us; speedup 1.0000x reference)
//
#include <hip/hip_runtime.h>
#include <hip/hip_bf16.h>

// Causal flash attention fwd: B=2,H=16,T=2048,D=64, fp32 in/out, bf16 MFMA.
#define T_   2048
#define D_   64
#define BH_  32
#define KBLK 32
#define QTILE 128          // 4 waves x 32 q-rows
#define NQT  (T_/QTILE)    // 16

typedef short bf16x8 __attribute__((ext_vector_type(8)));
typedef unsigned short u16x8 __attribute__((ext_vector_type(8)));
typedef unsigned int u32x4 __attribute__((ext_vector_type(4)));
typedef float f32x16 __attribute__((ext_vector_type(16)));

__device__ __forceinline__ unsigned short f2bf(float x) {
    union { float f; unsigned u; } v; v.f = x;
    unsigned r = v.u + 0x7FFFu + ((v.u >> 16) & 1u);   // RNE
    return (unsigned short)(r >> 16);
}
__device__ __forceinline__ unsigned pack2(float a, float b) {
    return (unsigned)f2bf(a) | ((unsigned)f2bf(b) << 16);
}

// LDS: K [32][72] u16 (4608 B) + V^T [64][40] u16 (5120 B); epilogue reuses as [4][32][65] f32.
#define SMEM_BYTES 33280

__global__ void fa_fwd(const float* __restrict__ q, const float* __restrict__ k,
                       const float* __restrict__ v, float* __restrict__ out) {
    __shared__ __align__(16) unsigned char smem[SMEM_BYTES];
    unsigned short* Klds = (unsigned short*)smem;            // [32][72]
    unsigned short* Vlds = (unsigned short*)(smem + 4608);   // V^T [64][40]
    float* Olds = (float*)smem;                              // epilogue [4][32][65]

    const int tid = threadIdx.x;
    const int w = tid >> 6, l = tid & 63, h = l >> 5, qr = l & 31;
    const int bid = blockIdx.x;
    const int bh = bid & (BH_ - 1);
    const int qt = (NQT - 1) - (bid >> 5);   // heavy (long-k) tiles first
    const int q0 = qt * QTILE;
    const int qbase = q0 + w * 32;           // wave's first q row
    const int qrow = qbase + qr;             // this lane's q row (col of S^T)

    // ---- Q fragments, pre-scaled by 1/sqrt(D). B-operand layout:
    // lane needs Q[qr = l&31][dk = f*16 + h*8 + j], j=0..7.
    bf16x8 qf[4];
    {
        const float* qp = q + ((size_t)(bh * T_ + qrow)) * D_ + h * 8;
        #pragma unroll
        for (int f = 0; f < 4; ++f) {
            float4 a = *(const float4*)(qp + f * 16);
            float4 b = *(const float4*)(qp + f * 16 + 4);
            u16x8 t;
            t[0] = f2bf(a.x * 0.125f); t[1] = f2bf(a.y * 0.125f);
            t[2] = f2bf(a.z * 0.125f); t[3] = f2bf(a.w * 0.125f);
            t[4] = f2bf(b.x * 0.125f); t[5] = f2bf(b.y * 0.125f);
            t[6] = f2bf(b.z * 0.125f); t[7] = f2bf(b.w * 0.125f);
            qf[f] = __builtin_bit_cast(bf16x8, t);
        }
    }

    f32x16 acc0 = {}, acc1 = {};             // O^T[d][qr], d 0-31 / 32-63
    float m = -__builtin_inff(), lsum = 0.f;

    const int nkt = (q0 + QTILE) / KBLK;
    const int krow = tid >> 3, kdc = (tid & 7) << 3;   // K staging map
    const int vkp = tid >> 4, vd0 = (tid & 15) << 2;   // V staging map

    for (int kt = 0; kt < nkt; ++kt) {
        const int kbase = kt * KBLK;

        // ---- stage K tile [32][64] -> Klds row-major (pad 72)
        {
            const float* kp = k + ((size_t)(bh * T_ + kbase + krow)) * D_ + kdc;
            float4 a = *(const float4*)kp, b = *(const float4*)(kp + 4);
            u16x8 t;
            t[0] = f2bf(a.x); t[1] = f2bf(a.y); t[2] = f2bf(a.z); t[3] = f2bf(a.w);
            t[4] = f2bf(b.x); t[5] = f2bf(b.y); t[6] = f2bf(b.z); t[7] = f2bf(b.w);
            *(u16x8*)(&Klds[krow * 72 + kdc]) = t;
        }
        // ---- stage V tile transposed -> Vlds[d][k] (pad 40), k-pairs packed per dword
        {
            const float* vp = v + ((size_t)(bh * T_ + kbase + 2 * vkp)) * D_ + vd0;
            float4 a = *(const float4*)vp;
            float4 b = *(const float4*)(vp + D_);
            const float* pa = &a.x; const float* pb = &b.x;
            #pragma unroll
            for (int i = 0; i < 4; ++i)
                *(unsigned*)(&Vlds[(vd0 + i) * 40 + 2 * vkp]) = pack2(pa[i], pb[i]);
        }
        __syncthreads();

        if (kbase <= qbase + 31) {           // tile not fully masked for this wave
            // ---- S^T = K_tile(32kc x 64d) . Q^T : A-frag = K rows, B-frag = Q regs
            f32x16 s = {};
            #pragma unroll
            for (int f = 0; f < 4; ++f) {
                bf16x8 aK = *(const bf16x8*)(&Klds[qr * 72 + f * 16 + h * 8]);
                s = __builtin_amdgcn_mfma_f32_32x32x16_bf16(aK, qf[f], s, 0, 0, 0);
            }
            // C layout: col = qr = l&31, row = kc = (reg&3) + 8*(reg>>2) + 4h
            if (kbase + KBLK - 1 > qbase) {  // diagonal tile: causal mask
                #pragma unroll
                for (int r = 0; r < 16; ++r) {
                    int kc = kbase + (r & 3) + ((r >> 2) << 3) + (h << 2);
                    if (kc > qrow) s[r] = -1e9f;
                }
            }
            // ---- online softmax: row is lane-local, one cross-half exchange
            float pm = s[0];
            #pragma unroll
            for (int r = 1; r < 16; ++r) pm = fmaxf(pm, s[r]);
            pm = fmaxf(pm, __shfl_xor(pm, 32));
            float mnew = fmaxf(m, pm);
            float corr = __expf(m - mnew);
            float p[16]; float ps = 0.f;
            #pragma unroll
            for (int r = 0; r < 16; ++r) { p[r] = __expf(s[r] - mnew); ps += p[r]; }
            ps += __shfl_xor(ps, 32);
            lsum = lsum * corr + ps;
            m = mnew;
            acc0 *= corr; acc1 *= corr;

            // ---- P -> bf16, rebuild PV B-fragments in-register.
            // quads: pk0/1 = kc{0-3}+4h, pk2/3 = {8-11}+4h, pk4/5 = {16-19}+4h, pk6/7 = {24-27}+4h
            unsigned pk0 = pack2(p[0],  p[1]),  pk1 = pack2(p[2],  p[3]);
            unsigned pk2 = pack2(p[4],  p[5]),  pk3 = pack2(p[6],  p[7]);
            unsigned pk4 = pack2(p[8],  p[9]),  pk5 = pack2(p[10], p[11]);
            unsigned pk6 = pack2(p[12], p[13]), pk7 = pack2(p[14], p[15]);
            unsigned o0 = __shfl_xor(pk0, 32), o1 = __shfl_xor(pk1, 32);
            unsigned o2 = __shfl_xor(pk2, 32), o3 = __shfl_xor(pk3, 32);
            unsigned o4 = __shfl_xor(pk4, 32), o5 = __shfl_xor(pk5, 32);
            unsigned o6 = __shfl_xor(pk6, 32), o7 = __shfl_xor(pk7, 32);
            // B-frag ks: lane holds P[qr][k = ks*16 + h*8 + j]
            u32x4 f0, f1;
            if (h == 0) {
                f0[0] = pk0; f0[1] = pk1; f0[2] = o0;  f0[3] = o1;   // k 0..7
                f1[0] = pk4; f1[1] = pk5; f1[2] = o4;  f1[3] = o5;   // k 16..23
            } else {
                f0[0] = o2;  f0[1] = o3;  f0[2] = pk2; f0[3] = pk3;  // k 8..15
                f1[0] = o6;  f1[1] = o7;  f1[2] = pk6; f1[3] = pk7;  // k 24..31
            }
            bf16x8 bp0 = __builtin_bit_cast(bf16x8, f0);
            bf16x8 bp1 = __builtin_bit_cast(bf16x8, f1);

            // ---- O^T += V^T(d x k) . P^T(k x qr); A-frag rows = d from Vlds
            bf16x8 aV;
            aV = *(const bf16x8*)(&Vlds[qr * 40 + h * 8]);
            acc0 = __builtin_amdgcn_mfma_f32_32x32x16_bf16(aV, bp0, acc0, 0, 0, 0);
            aV = *(const bf16x8*)(&Vlds[qr * 40 + 16 + h * 8]);
            acc0 = __builtin_amdgcn_mfma_f32_32x32x16_bf16(aV, bp1, acc0, 0, 0, 0);
            aV = *(const bf16x8*)(&Vlds[(32 + qr) * 40 + h * 8]);
            acc1 = __builtin_amdgcn_mfma_f32_32x32x16_bf16(aV, bp0, acc1, 0, 0, 0);
            aV = *(const bf16x8*)(&Vlds[(32 + qr) * 40 + 16 + h * 8]);
            acc1 = __builtin_amdgcn_mfma_f32_32x32x16_bf16(aV, bp1, acc1, 0, 0, 0);
        }
        __syncthreads();
    }

    // ---- epilogue: O^T -> LDS transpose -> coalesced float4 stores
    float inv = 1.0f / lsum;
    float* ol = Olds + w * 32 * 65;
    #pragma unroll
    for (int reg = 0; reg < 16; ++reg) {
        int d = (reg & 3) + ((reg >> 2) << 3) + (h << 2);
        ol[qr * 65 + d]      = acc0[reg] * inv;
        ol[qr * 65 + 32 + d] = acc1[reg] * inv;
    }
    __syncthreads();
    float* ob = out + ((size_t)(bh * T_ + q0 + w * 32)) * D_;
    #pragma unroll
    for (int i = 0; i < 8; ++i) {
        int flat = i * 64 + l;
        int row = flat >> 4, c4 = (flat & 15) << 2;
        float4 val;
        val.x = ol[row * 65 + c4];
        val.y = ol[row * 65 + c4 + 1];
        val.z = ol[row * 65 + c4 + 2];
        val.w = ol[row * 65 + c4 + 3];
        *(float4*)(&ob[row * D_ + c4]) = val;
    }
}

extern "C" void kernel_launch(void* const* d_in, const int* in_sizes, int n_in,
                              void* d_out, int out_size, void* d_ws, size_t ws_size,
                              hipStream_t stream) {
    const float* q = (const float*)d_in[0];
    const float* k = (const float*)d_in[1];
    const float* v = (const float*)d_in[2];
    float* out = (float*)d_out;
    fa_fwd<<<dim3(BH_ * NQT), dim3(256), 0, stream>>>(q, k, v, out);
}

// Round 4
// 84.191 us; speedup vs baseline: 1.0785x; 1.0785x over previous
//
#include <hip/hip_runtime.h>
#include <hip/hip_bf16.h>

// Causal flash attention fwd: B=2,H=16,T=2048,D=64, fp32 in/out, bf16 MFMA.
// Round 4 = round 3 + correctness fix: inline-asm v_permlane32_swap_b32 with a
// copied operand could register-coalesce (v_permlane32_swap v5,v5 -> half-swap,
// fmax(v5,v5) drops own half -> wrong max -> exp2 overflow -> inf). Use the
// two-result __builtin_amdgcn_permlane32_swap instead.
#define T_    2048
#define D_    64
#define BH_   32
#define KBLK  32
#define QT2   64
#define NQT2  32           // T_/QT2

typedef short bf16x8 __attribute__((ext_vector_type(8)));
typedef unsigned short u16x8 __attribute__((ext_vector_type(8)));
typedef unsigned int u32x2 __attribute__((ext_vector_type(2)));
typedef unsigned int u32x4 __attribute__((ext_vector_type(4)));
typedef float f32x16 __attribute__((ext_vector_type(16)));

__device__ __forceinline__ float exp2fast(float x) {
    return __builtin_amdgcn_exp2f(x);          // v_exp_f32 (input in log2 units)
}
__device__ __forceinline__ unsigned short f2bf_rne(float x) {
    union { float f; unsigned u; } v; v.f = x;
    unsigned r = v.u + 0x7FFFu + ((v.u >> 16) & 1u);
    return (unsigned short)(r >> 16);
}
// round-half-up bf16 pair pack (bias ~2^-17 relative; fine vs 7.7e-2 threshold)
__device__ __forceinline__ unsigned pack2_rn(float a, float b) {
    unsigned au = __builtin_bit_cast(unsigned, a) + 0x8000u;
    unsigned bu = __builtin_bit_cast(unsigned, b) + 0x8000u;
    return (au >> 16) | (bu & 0xFFFF0000u);
}
// permlane32_swap, value semantics: a' = {a.lo31, b.lo31}, b' = {a.hi31, b.hi31}
__device__ __forceinline__ void swapu(unsigned& a, unsigned& b) {
    u32x2 r = __builtin_amdgcn_permlane32_swap(a, b, false, false);
    a = r[0]; b = r[1];
}
// cross-half reduce helper: returns value from partner half (lane^32)
__device__ __forceinline__ float xhalf(float x) {
    unsigned u = __builtin_bit_cast(unsigned, x);
    u32x2 r = __builtin_amdgcn_permlane32_swap(u, u, false, false);
    // lane<32: r[1] holds x[lane+32]; lane>=32: r[0] holds x[lane-32]
    unsigned lo = r[0], hi = r[1];
    // select the partner word per half: lanes<32 want hi, lanes>=32 want lo
    // (branchless: both halves compute both; use lane bit)
    return __builtin_bit_cast(float, ( __lane_id() & 32 ) ? lo : hi);
}

// LDS (u16 units): K tiles 4 x [32][72] = 9216 u16; V tiles 4 x [64][40] = 10240 u16
// total 19456 u16 = 38912 B. Epilogue overlays (f32): m[2][64], l[2][64],
// a[2][64][33], ot[2][32][65] -> max 34560 B.
#define SMEM_BYTES 38912

__global__ __launch_bounds__(256, 4)
void fa_fwd(const float* __restrict__ q, const float* __restrict__ k,
            const float* __restrict__ v, float* __restrict__ out) {
    __shared__ __align__(16) unsigned char smem[SMEM_BYTES];
    unsigned short* KB = (unsigned short*)smem;
    unsigned short* VB = KB + 9216;
    float* fb = (float*)smem;

    const int tid = threadIdx.x;
    const int w = tid >> 6, l = tid & 63, h = l >> 5, qr = l & 31;
    const int g = w & 1;          // q-wave: rows g*32..g*32+31 of the tile
    const int sid = w >> 1;       // k-stream: tiles 2t+sid
    const int bid = blockIdx.x;
    const int bh = bid & 31;
    const int j = bid >> 5;
    const int qt = (j < 16) ? (31 - j) : (j - 16);   // constant per-CU work sum
    const int q0 = qt * QT2;
    const int qbase = q0 + g * 32;

    // ---- Q fragments: scale = (1/sqrt(64)) * log2(e)  (exp2-unit softmax)
    const float QS = 0.18033688011112042f;
    bf16x8 qf[4];
    {
        const float* qp = q + ((size_t)(bh * T_ + qbase + qr)) * D_ + h * 8;
        #pragma unroll
        for (int f = 0; f < 4; ++f) {
            float4 a = *(const float4*)(qp + f * 16);
            float4 b = *(const float4*)(qp + f * 16 + 4);
            u16x8 t;
            t[0] = f2bf_rne(a.x * QS); t[1] = f2bf_rne(a.y * QS);
            t[2] = f2bf_rne(a.z * QS); t[3] = f2bf_rne(a.w * QS);
            t[4] = f2bf_rne(b.x * QS); t[5] = f2bf_rne(b.y * QS);
            t[6] = f2bf_rne(b.z * QS); t[7] = f2bf_rne(b.w * QS);
            qf[f] = __builtin_bit_cast(bf16x8, t);
        }
    }

    f32x16 acc0 = {}, acc1 = {};                 // O^T[d][qr], d 0-31 / 32-63 (partial)
    float m = -__builtin_inff(), lsum = 0.f;

    const int nkt = qt + 1;                      // tiles per stream
    const int st = tid & 127;                    // staging lane within stream
    const int krow = st >> 2, kd0 = (st & 3) << 4;
    const int vkp0 = st >> 4, vd0 = (st & 15) << 2;
    const float* Kg = k + (size_t)(bh * T_) * D_;
    const float* Vg = v + (size_t)(bh * T_) * D_;

    float4 kA, kB2, kC, kD, vA, vB, vC, vD;      // prefetch regs (32 VGPR)

#define STAGE_LOAD(kb) do { \
    const float* kp_ = Kg + (size_t)((kb) + krow) * D_ + kd0; \
    kA = *(const float4*)kp_;        kB2 = *(const float4*)(kp_ + 4); \
    kC = *(const float4*)(kp_ + 8);  kD  = *(const float4*)(kp_ + 12); \
    const float* vp_ = Vg + (size_t)((kb) + 2 * vkp0) * D_ + vd0; \
    vA = *(const float4*)vp_;              vB = *(const float4*)(vp_ + D_); \
    vC = *(const float4*)(vp_ + 16 * D_);  vD = *(const float4*)(vp_ + 17 * D_); \
} while (0)

#define STAGE_WRITE(buf) do { \
    unsigned short* Kt_ = KB + (sid * 2 + (buf)) * 2304; \
    unsigned short* Vt_ = VB + (sid * 2 + (buf)) * 2560; \
    unsigned* kw = (unsigned*)(Kt_ + krow * 72 + kd0); \
    u32x4 w0_ = { pack2_rn(kA.x, kA.y), pack2_rn(kA.z, kA.w), \
                  pack2_rn(kB2.x, kB2.y), pack2_rn(kB2.z, kB2.w) }; \
    u32x4 w1_ = { pack2_rn(kC.x, kC.y), pack2_rn(kC.z, kC.w), \
                  pack2_rn(kD.x, kD.y), pack2_rn(kD.z, kD.w) }; \
    *(u32x4*)kw = w0_; *(u32x4*)(kw + 4) = w1_; \
    { const float* pa_ = &vA.x; const float* pb_ = &vB.x; \
      _Pragma("unroll") \
      for (int i_ = 0; i_ < 4; ++i_) \
        *(unsigned*)(Vt_ + (vd0 + i_) * 40 + 2 * vkp0) = pack2_rn(pa_[i_], pb_[i_]); } \
    { const float* pa_ = &vC.x; const float* pb_ = &vD.x; \
      _Pragma("unroll") \
      for (int i_ = 0; i_ < 4; ++i_) \
        *(unsigned*)(Vt_ + (vd0 + i_) * 40 + 2 * (vkp0 + 8)) = pack2_rn(pa_[i_], pb_[i_]); } \
} while (0)

    // prologue: stage tile 0 of this stream
    STAGE_LOAD(sid * KBLK);
    STAGE_WRITE(0);
    __syncthreads();

    int cur = 0;
    for (int t = 0; t < nkt; ++t) {
        const int kbase = (2 * t + sid) * KBLK;
        const bool more = (t + 1 < nkt);
        if (more) STAGE_LOAD((2 * (t + 1) + sid) * KBLK);   // issue early (T14)

        if (kbase <= qbase + 31) {
            unsigned short* Kt = KB + (sid * 2 + cur) * 2304;
            unsigned short* Vt = VB + (sid * 2 + cur) * 2560;
            // ---- S^T = K_tile . Q^T
            f32x16 sv = {};
            __builtin_amdgcn_s_setprio(1);
            #pragma unroll
            for (int f = 0; f < 4; ++f) {
                bf16x8 aK = *(const bf16x8*)(Kt + qr * 72 + f * 16 + h * 8);
                sv = __builtin_amdgcn_mfma_f32_32x32x16_bf16(aK, qf[f], sv, 0, 0, 0);
            }
            __builtin_amdgcn_s_setprio(0);
            if (kbase == qbase) {                 // diagonal tile
                #pragma unroll
                for (int r = 0; r < 16; ++r) {
                    int kc = (r & 3) + ((r >> 2) << 3) + (h << 2);
                    if (kc > qr) sv[r] = -1e9f;
                }
            }
            // ---- online softmax (exp2 units), cross-half via permlane32_swap
            float pm = sv[0];
            #pragma unroll
            for (int r = 1; r < 16; ++r) pm = fmaxf(pm, sv[r]);
            pm = fmaxf(pm, xhalf(pm));
            float mnew = fmaxf(m, pm);
            float corr = exp2fast(m - mnew);
            m = mnew;
            float ps = 0.f;
            #pragma unroll
            for (int r = 0; r < 16; ++r) { sv[r] = exp2fast(sv[r] - mnew); ps += sv[r]; }
            ps += xhalf(ps);
            lsum = lsum * corr + ps;
            acc0 *= corr; acc1 *= corr;
            // ---- P -> bf16 fragments: 8 packs + 4 permlane swaps
            unsigned w00 = pack2_rn(sv[0],  sv[1]),  w01 = pack2_rn(sv[2],  sv[3]);
            unsigned w10 = pack2_rn(sv[4],  sv[5]),  w11 = pack2_rn(sv[6],  sv[7]);
            unsigned w20 = pack2_rn(sv[8],  sv[9]),  w21 = pack2_rn(sv[10], sv[11]);
            unsigned w30 = pack2_rn(sv[12], sv[13]), w31 = pack2_rn(sv[14], sv[15]);
            swapu(w00, w10); swapu(w01, w11); swapu(w20, w30); swapu(w21, w31);
            u32x4 f0v = { w00, w01, w10, w11 };
            u32x4 f1v = { w20, w21, w30, w31 };
            bf16x8 bp0 = __builtin_bit_cast(bf16x8, f0v);
            bf16x8 bp1 = __builtin_bit_cast(bf16x8, f1v);
            // ---- O^T += V^T . P^T
            __builtin_amdgcn_s_setprio(1);
            bf16x8 aV;
            aV = *(const bf16x8*)(Vt + qr * 40 + h * 8);
            acc0 = __builtin_amdgcn_mfma_f32_32x32x16_bf16(aV, bp0, acc0, 0, 0, 0);
            aV = *(const bf16x8*)(Vt + qr * 40 + 16 + h * 8);
            acc0 = __builtin_amdgcn_mfma_f32_32x32x16_bf16(aV, bp1, acc0, 0, 0, 0);
            aV = *(const bf16x8*)(Vt + (32 + qr) * 40 + h * 8);
            acc1 = __builtin_amdgcn_mfma_f32_32x32x16_bf16(aV, bp0, acc1, 0, 0, 0);
            aV = *(const bf16x8*)(Vt + (32 + qr) * 40 + 16 + h * 8);
            acc1 = __builtin_amdgcn_mfma_f32_32x32x16_bf16(aV, bp1, acc1, 0, 0, 0);
            __builtin_amdgcn_s_setprio(0);
        }

        if (more) STAGE_WRITE(cur ^ 1);          // write next tile (other buffer)
        __syncthreads();                          // single barrier per iteration
        cur ^= 1;
    }

    // ---- epilogue: merge the two k-streams, transpose, coalesced store
    float* mb = fb;                 // [2][64]
    float* lb = fb + 128;           // [2][64]
    float* ab = fb + 256;           // [2][64][33]  (pad 33: conflict-free)
    float* ot = fb + 4480;          // [2][32][65]
    if (sid == 1) {
        mb[g * 64 + l] = m;
        lb[g * 64 + l] = lsum;
        float* ap = ab + (g * 64 + l) * 33;
        #pragma unroll
        for (int r = 0; r < 16; ++r) { ap[r] = acc0[r]; ap[16 + r] = acc1[r]; }
    }
    __syncthreads();
    if (sid == 0) {
        float m1 = mb[g * 64 + l], l1 = lb[g * 64 + l];
        float ms = fmaxf(m, m1);
        float c0 = exp2fast(m - ms), c1 = exp2fast(m1 - ms);
        float inv = 1.0f / (lsum * c0 + l1 * c1);
        const float* ap = ab + (g * 64 + l) * 33;
        float* og = ot + g * 2080;   // [32][65]
        #pragma unroll
        for (int r = 0; r < 16; ++r) {
            int d = (r & 3) + ((r >> 2) << 3) + (h << 2);
            og[qr * 65 + d]      = (acc0[r] * c0 + ap[r]      * c1) * inv;
            og[qr * 65 + 32 + d] = (acc1[r] * c0 + ap[16 + r] * c1) * inv;
        }
    }
    __syncthreads();
    float* ob = out + (size_t)(bh * T_ + q0) * D_;
    #pragma unroll
    for (int i = 0; i < 4; ++i) {
        int idx = i * 256 + tid;                 // float4 units of the 64x64 tile
        int row = idx >> 4, c4 = (idx & 15) << 2;
        const float* src = ot + (row >> 5) * 2080 + (row & 31) * 65 + c4;
        float4 val; val.x = src[0]; val.y = src[1]; val.z = src[2]; val.w = src[3];
        *(float4*)(ob + row * D_ + c4) = val;
    }
#undef STAGE_LOAD
#undef STAGE_WRITE
}

extern "C" void kernel_launch(void* const* d_in, const int* in_sizes, int n_in,
                              void* d_out, int out_size, void* d_ws, size_t ws_size,
                              hipStream_t stream) {
    const float* q = (const float*)d_in[0];
    const float* k = (const float*)d_in[1];
    const float* v = (const float*)d_in[2];
    float* out = (float*)d_out;
    fa_fwd<<<dim3(BH_ * NQT2), dim3(256), 0, stream>>>(q, k, v, out);
}

// Round 5
// 75.405 us; speedup vs baseline: 1.2041x; 1.1165x over previous
//
#include <hip/hip_runtime.h>
#include <hip/hip_bf16.h>

// Causal flash attention fwd: B=2,H=16,T=2048,D=64, fp32 in/out, bf16 MFMA.
// Round 5: uniform-work pairing (block p does qt=31-p then qt=p -> 17 iters
// for EVERY block), 512-thread blocks = 2 q-halves x 4 k-streams, grid 512 =
// exactly 2 blocks/CU sustained (constant 50% occupancy, zero tail).
#define T_    2048
#define D_    64
#define BH_   32
#define KBLK  32
#define QT2   64

typedef short bf16x8 __attribute__((ext_vector_type(8)));
typedef unsigned short u16x8 __attribute__((ext_vector_type(8)));
typedef unsigned int u32x2 __attribute__((ext_vector_type(2)));
typedef unsigned int u32x4 __attribute__((ext_vector_type(4)));
typedef float f32x16 __attribute__((ext_vector_type(16)));

__device__ __forceinline__ float exp2fast(float x) {
    return __builtin_amdgcn_exp2f(x);          // v_exp_f32 (input in log2 units)
}
__device__ __forceinline__ unsigned short f2bf_rne(float x) {
    union { float f; unsigned u; } v; v.f = x;
    unsigned r = v.u + 0x7FFFu + ((v.u >> 16) & 1u);
    return (unsigned short)(r >> 16);
}
// round-half-up bf16 pair pack (bias ~2^-17 relative; fine vs 7.7e-2 threshold)
__device__ __forceinline__ unsigned pack2_rn(float a, float b) {
    unsigned au = __builtin_bit_cast(unsigned, a) + 0x8000u;
    unsigned bu = __builtin_bit_cast(unsigned, b) + 0x8000u;
    return (au >> 16) | (bu & 0xFFFF0000u);
}
// permlane32_swap, value semantics: a' = {a.lo31, b.lo31}, b' = {a.hi31, b.hi31}
__device__ __forceinline__ void swapu(unsigned& a, unsigned& b) {
    u32x2 r = __builtin_amdgcn_permlane32_swap(a, b, false, false);
    a = r[0]; b = r[1];
}
// cross-half reduce helper: returns value from partner half (lane^32)
__device__ __forceinline__ float xhalf(float x) {
    unsigned u = __builtin_bit_cast(unsigned, x);
    u32x2 r = __builtin_amdgcn_permlane32_swap(u, u, false, false);
    unsigned lo = r[0], hi = r[1];
    return __builtin_bit_cast(float, (__lane_id() & 32) ? lo : hi);
}

// LDS (u16): K 8 x [32][72] = 18432 u16; V 8 x [64][40] = 20480 u16 -> 77824 B.
// Epilogue overlay (f32): m[3][128], l[3][128], acc[3][128][33], ot[2][32][65]
// = 17600 f32 = 70400 B <= 77824.
#define SMEM_BYTES 77824

__global__ __launch_bounds__(512, 4)
void fa_fwd(const float* __restrict__ q, const float* __restrict__ k,
            const float* __restrict__ v, float* __restrict__ out) {
    __shared__ __align__(16) unsigned char smem[SMEM_BYTES];
    unsigned short* KB = (unsigned short*)smem;
    unsigned short* VB = KB + 18432;
    float* fb = (float*)smem;

    const int tid = threadIdx.x;
    const int w = tid >> 6, l = tid & 63, h = l >> 5, qr = l & 31;
    const int g = w & 1;          // q-half: rows g*32..g*32+31 of the 64-row tile
    const int sid = w >> 1;       // k-stream 0..3: handles k-tiles kidx = 4t+sid
    const int bid = blockIdx.x;
    const int bh = bid & 31;
    const int p = bid >> 5;       // pair index 0..15

    const int st = tid & 127;     // staging lane within 128-thread stream group
    const int krow = st >> 2, kd0 = (st & 3) << 4;
    const int vkp0 = st >> 4, vd0 = (st & 15) << 2;
    const float* Kg = k + (size_t)(bh * T_) * D_;
    const float* Vg = v + (size_t)(bh * T_) * D_;
    const float QS = 0.18033688011112042f;   // (1/sqrt(64)) * log2(e)

    float4 kA, kB2, kC, kD, vA, vB, vC, vD;  // prefetch regs

#define STAGE_LOAD(kb) do { \
    const float* kp_ = Kg + (size_t)((kb) + krow) * D_ + kd0; \
    kA = *(const float4*)kp_;        kB2 = *(const float4*)(kp_ + 4); \
    kC = *(const float4*)(kp_ + 8);  kD  = *(const float4*)(kp_ + 12); \
    const float* vp_ = Vg + (size_t)((kb) + 2 * vkp0) * D_ + vd0; \
    vA = *(const float4*)vp_;              vB = *(const float4*)(vp_ + D_); \
    vC = *(const float4*)(vp_ + 16 * D_);  vD = *(const float4*)(vp_ + 17 * D_); \
} while (0)

#define STAGE_WRITE(buf) do { \
    unsigned short* Kt_ = KB + (sid * 2 + (buf)) * 2304; \
    unsigned short* Vt_ = VB + (sid * 2 + (buf)) * 2560; \
    unsigned* kw = (unsigned*)(Kt_ + krow * 72 + kd0); \
    u32x4 w0_ = { pack2_rn(kA.x, kA.y), pack2_rn(kA.z, kA.w), \
                  pack2_rn(kB2.x, kB2.y), pack2_rn(kB2.z, kB2.w) }; \
    u32x4 w1_ = { pack2_rn(kC.x, kC.y), pack2_rn(kC.z, kC.w), \
                  pack2_rn(kD.x, kD.y), pack2_rn(kD.z, kD.w) }; \
    *(u32x4*)kw = w0_; *(u32x4*)(kw + 4) = w1_; \
    { const float* pa_ = &vA.x; const float* pb_ = &vB.x; \
      _Pragma("unroll") \
      for (int i_ = 0; i_ < 4; ++i_) \
        *(unsigned*)(Vt_ + (vd0 + i_) * 40 + 2 * vkp0) = pack2_rn(pa_[i_], pb_[i_]); } \
    { const float* pa_ = &vC.x; const float* pb_ = &vD.x; \
      _Pragma("unroll") \
      for (int i_ = 0; i_ < 4; ++i_) \
        *(unsigned*)(Vt_ + (vd0 + i_) * 40 + 2 * (vkp0 + 8)) = pack2_rn(pa_[i_], pb_[i_]); } \
} while (0)

    #pragma unroll 1
    for (int half = 0; half < 2; ++half) {
        const int qt = half ? p : (31 - p);
        const int q0 = qt * QT2;
        const int qbase = q0 + g * 32;
        const int nIter = (qt + 2) >> 1;     // ceil((2qt+2)/4)
        const int kmax = 2 * qt + 1;         // last needed 32-k tile index

        // ---- Q fragments for this tile
        bf16x8 qf[4];
        {
            const float* qp = q + ((size_t)(bh * T_ + qbase + qr)) * D_ + h * 8;
            #pragma unroll
            for (int f = 0; f < 4; ++f) {
                float4 a = *(const float4*)(qp + f * 16);
                float4 b = *(const float4*)(qp + f * 16 + 4);
                u16x8 t;
                t[0] = f2bf_rne(a.x * QS); t[1] = f2bf_rne(a.y * QS);
                t[2] = f2bf_rne(a.z * QS); t[3] = f2bf_rne(a.w * QS);
                t[4] = f2bf_rne(b.x * QS); t[5] = f2bf_rne(b.y * QS);
                t[6] = f2bf_rne(b.z * QS); t[7] = f2bf_rne(b.w * QS);
                qf[f] = __builtin_bit_cast(bf16x8, t);
            }
        }

        f32x16 acc0 = {}, acc1 = {};         // O^T[d][qr] partial for this stream
        float m = -__builtin_inff(), lsum = 0.f;

        // prologue: stage this stream's tile 0 (kidx = sid)
        if (sid <= kmax) { STAGE_LOAD(sid * KBLK); STAGE_WRITE(0); }
        __syncthreads();

        int cur = 0;
        for (int t = 0; t < nIter; ++t) {
            const int kbase = (4 * t + sid) * KBLK;
            const int kn = 4 * (t + 1) + sid;
            const bool needN = (t + 1 < nIter) && (kn <= kmax);
            if (needN) STAGE_LOAD(kn * KBLK);    // issue early (T14)

            if (kbase <= qbase + 31) {
                unsigned short* Kt = KB + (sid * 2 + cur) * 2304;
                unsigned short* Vt = VB + (sid * 2 + cur) * 2560;
                // ---- S^T = K_tile . Q^T
                f32x16 sv = {};
                __builtin_amdgcn_s_setprio(1);
                #pragma unroll
                for (int f = 0; f < 4; ++f) {
                    bf16x8 aK = *(const bf16x8*)(Kt + qr * 72 + f * 16 + h * 8);
                    sv = __builtin_amdgcn_mfma_f32_32x32x16_bf16(aK, qf[f], sv, 0, 0, 0);
                }
                __builtin_amdgcn_s_setprio(0);
                if (kbase == qbase) {            // diagonal tile: causal mask
                    #pragma unroll
                    for (int r = 0; r < 16; ++r) {
                        int kc = (r & 3) + ((r >> 2) << 3) + (h << 2);
                        if (kc > qr) sv[r] = -1e9f;
                    }
                }
                // ---- online softmax (exp2 units)
                float pm = sv[0];
                #pragma unroll
                for (int r = 1; r < 16; ++r) pm = fmaxf(pm, sv[r]);
                pm = fmaxf(pm, xhalf(pm));
                float mnew = fmaxf(m, pm);
                float corr = exp2fast(m - mnew);
                m = mnew;
                float ps = 0.f;
                #pragma unroll
                for (int r = 0; r < 16; ++r) { sv[r] = exp2fast(sv[r] - mnew); ps += sv[r]; }
                ps += xhalf(ps);
                lsum = lsum * corr + ps;
                acc0 *= corr; acc1 *= corr;
                // ---- P -> bf16 PV fragments: 8 packs + 4 permlane swaps
                unsigned w00 = pack2_rn(sv[0],  sv[1]),  w01 = pack2_rn(sv[2],  sv[3]);
                unsigned w10 = pack2_rn(sv[4],  sv[5]),  w11 = pack2_rn(sv[6],  sv[7]);
                unsigned w20 = pack2_rn(sv[8],  sv[9]),  w21 = pack2_rn(sv[10], sv[11]);
                unsigned w30 = pack2_rn(sv[12], sv[13]), w31 = pack2_rn(sv[14], sv[15]);
                swapu(w00, w10); swapu(w01, w11); swapu(w20, w30); swapu(w21, w31);
                u32x4 f0v = { w00, w01, w10, w11 };
                u32x4 f1v = { w20, w21, w30, w31 };
                bf16x8 bp0 = __builtin_bit_cast(bf16x8, f0v);
                bf16x8 bp1 = __builtin_bit_cast(bf16x8, f1v);
                // ---- O^T += V^T . P^T
                __builtin_amdgcn_s_setprio(1);
                bf16x8 aV;
                aV = *(const bf16x8*)(Vt + qr * 40 + h * 8);
                acc0 = __builtin_amdgcn_mfma_f32_32x32x16_bf16(aV, bp0, acc0, 0, 0, 0);
                aV = *(const bf16x8*)(Vt + qr * 40 + 16 + h * 8);
                acc0 = __builtin_amdgcn_mfma_f32_32x32x16_bf16(aV, bp1, acc0, 0, 0, 0);
                aV = *(const bf16x8*)(Vt + (32 + qr) * 40 + h * 8);
                acc1 = __builtin_amdgcn_mfma_f32_32x32x16_bf16(aV, bp0, acc1, 0, 0, 0);
                aV = *(const bf16x8*)(Vt + (32 + qr) * 40 + 16 + h * 8);
                acc1 = __builtin_amdgcn_mfma_f32_32x32x16_bf16(aV, bp1, acc1, 0, 0, 0);
                __builtin_amdgcn_s_setprio(0);
            }

            if (needN) STAGE_WRITE(cur ^ 1);
            __syncthreads();
            cur ^= 1;
        }

        // ---- epilogue: 4-stream merge, transpose, coalesced store
        float* mbuf = fb;                    // [3][128]
        float* lbuf = fb + 384;              // [3][128]
        float* abuf = fb + 768;              // [3][128][33]
        float* ot   = fb + 13440;            // [2][32][65]
        const int row = g * 64 + l;
        if (sid != 0) {
            const int ps2 = sid - 1;
            mbuf[ps2 * 128 + row] = m;
            lbuf[ps2 * 128 + row] = lsum;
            float* ap = abuf + (ps2 * 128 + row) * 33;
            #pragma unroll
            for (int r = 0; r < 16; ++r) { ap[r] = acc0[r]; ap[16 + r] = acc1[r]; }
        }
        __syncthreads();
        if (sid == 0) {
            float m1 = mbuf[row], m2 = mbuf[128 + row], m3 = mbuf[256 + row];
            float ms = fmaxf(fmaxf(m, m1), fmaxf(m2, m3));
            float c0 = exp2fast(m - ms),  c1 = exp2fast(m1 - ms);
            float c2 = exp2fast(m2 - ms), c3 = exp2fast(m3 - ms);
            float lt = lsum * c0 + lbuf[row] * c1 + lbuf[128 + row] * c2 + lbuf[256 + row] * c3;
            float inv = 1.0f / lt;
            const float* a1 = abuf + row * 33;
            const float* a2 = abuf + (128 + row) * 33;
            const float* a3 = abuf + (256 + row) * 33;
            float* og = ot + g * 2080;       // [32][65]
            #pragma unroll
            for (int r = 0; r < 16; ++r) {
                int d = (r & 3) + ((r >> 2) << 3) + (h << 2);
                og[qr * 65 + d] =
                    (acc0[r] * c0 + a1[r] * c1 + a2[r] * c2 + a3[r] * c3) * inv;
                og[qr * 65 + 32 + d] =
                    (acc1[r] * c0 + a1[16 + r] * c1 + a2[16 + r] * c2 + a3[16 + r] * c3) * inv;
            }
        }
        __syncthreads();
        float* ob = out + (size_t)(bh * T_ + q0) * D_;
        #pragma unroll
        for (int i = 0; i < 2; ++i) {
            int idx = i * 512 + tid;         // float4 units of the 64x64 tile
            int r2 = idx >> 4, c4 = (idx & 15) << 2;
            const float* src = ot + (r2 >> 5) * 2080 + (r2 & 31) * 65 + c4;
            float4 val; val.x = src[0]; val.y = src[1]; val.z = src[2]; val.w = src[3];
            *(float4*)(ob + r2 * D_ + c4) = val;
        }
        __syncthreads();                     // protect ot before next half's staging
    }
#undef STAGE_LOAD
#undef STAGE_WRITE
}

extern "C" void kernel_launch(void* const* d_in, const int* in_sizes, int n_in,
                              void* d_out, int out_size, void* d_ws, size_t ws_size,
                              hipStream_t stream) {
    const float* q = (const float*)d_in[0];
    const float* k = (const float*)d_in[1];
    const float* v = (const float*)d_in[2];
    float* out = (float*)d_out;
    fa_fwd<<<dim3(BH_ * 16), dim3(512), 0, stream>>>(q, k, v, out);
}

// Round 6
// 60.008 us; speedup vs baseline: 1.5131x; 1.2566x over previous
//
#include <hip/hip_runtime.h>
#include <hip/hip_bf16.h>

// Causal flash attention fwd: B=2,H=16,T=2048,D=64, fp32 in/out, bf16 MFMA.
// Round 6: (1) prep kernel pre-converts K,V -> bf16 into d_ws in swizzled
// LDS-image layout (conversion hoisted out of the ~17x re-staging loop);
// (2) main-loop staging = global_load_lds 16B DMA (no VALU, no regs);
// (3) defer-max rescale skip (THR=8 log2 units); tree max/sum.
#define T_    2048
#define D_    64
#define BH_   32
#define KBLK  32
#define QT2   64

typedef short bf16x8 __attribute__((ext_vector_type(8)));
typedef unsigned short u16x8 __attribute__((ext_vector_type(8)));
typedef unsigned int u32x2 __attribute__((ext_vector_type(2)));
typedef unsigned int u32x4 __attribute__((ext_vector_type(4)));
typedef float f32x16 __attribute__((ext_vector_type(16)));

__device__ __forceinline__ float exp2fast(float x) {
    return __builtin_amdgcn_exp2f(x);          // v_exp_f32 (log2 units)
}
__device__ __forceinline__ unsigned short f2bf_rne(float x) {
    union { float f; unsigned u; } v; v.f = x;
    unsigned r = v.u + 0x7FFFu + ((v.u >> 16) & 1u);
    return (unsigned short)(r >> 16);
}
__device__ __forceinline__ unsigned pack2_rn(float a, float b) {
    unsigned au = __builtin_bit_cast(unsigned, a) + 0x8000u;
    unsigned bu = __builtin_bit_cast(unsigned, b) + 0x8000u;
    return (au >> 16) | (bu & 0xFFFF0000u);
}
__device__ __forceinline__ void swapu(unsigned& a, unsigned& b) {
    u32x2 r = __builtin_amdgcn_permlane32_swap(a, b, false, false);
    a = r[0]; b = r[1];
}
__device__ __forceinline__ float xhalf(float x) {
    unsigned u = __builtin_bit_cast(unsigned, x);
    u32x2 r = __builtin_amdgcn_permlane32_swap(u, u, false, false);
    unsigned lo = r[0], hi = r[1];
    return __builtin_bit_cast(float, (__lane_id() & 32) ? lo : hi);
}
__device__ __forceinline__ void gl16(const void* g, void* l) {
    __builtin_amdgcn_global_load_lds(
        (const __attribute__((address_space(1))) unsigned*)g,
        (__attribute__((address_space(3))) unsigned*)l, 16, 0, 0);
}

// ---- prep: K,V fp32 -> bf16 into ws, per-(bh,32k-tile) 4KB images.
// K image: data chunk (row, c) [16B, cols c*8..c*8+7] at byte row*128 + (c^(row&7))*16.
// V image: transposed [d][k] bf16, k-pairs per dword; data chunk (d, c)
// [k = c*8..c*8+7] at byte d*64 + (c^(d&3))*16, dwords in natural order.
__global__ __launch_bounds__(256)
void prep(const float* __restrict__ k, const float* __restrict__ v,
          unsigned short* __restrict__ kws, unsigned short* __restrict__ vws) {
    const int bid = blockIdx.x, tid = threadIdx.x;
    if (bid < 2048) {
        int gid = bid * 256 + tid;
        int n = gid & 255, tl = (gid >> 8) & 63, bh = gid >> 14;
        int row = n >> 3, c = n & 7, cs = c ^ (row & 7);
        const float* src = k + ((size_t)(bh * T_ + tl * 32 + row)) * D_ + c * 8;
        float4 a = *(const float4*)src, b = *(const float4*)(src + 4);
        u16x8 t;
        t[0] = f2bf_rne(a.x); t[1] = f2bf_rne(a.y); t[2] = f2bf_rne(a.z); t[3] = f2bf_rne(a.w);
        t[4] = f2bf_rne(b.x); t[5] = f2bf_rne(b.y); t[6] = f2bf_rne(b.z); t[7] = f2bf_rne(b.w);
        *(u16x8*)(kws + (size_t)(bh * 64 + tl) * 2048 + row * 64 + cs * 8) = t;
    } else {
        int gid = (bid - 2048) * 256 + tid;
        int dg = gid & 15, kp = (gid >> 4) & 15, tl = (gid >> 8) & 63, bh = gid >> 14;
        int k0 = tl * 32 + 2 * kp, d0 = dg * 4;
        const float* s0 = v + ((size_t)(bh * T_ + k0)) * D_ + d0;
        float4 a = *(const float4*)s0;
        float4 b = *(const float4*)(s0 + D_);
        unsigned* dst = (unsigned*)(vws + (size_t)(bh * 64 + tl) * 2048);
        const float* pa = &a.x; const float* pb = &b.x;
        #pragma unroll
        for (int i = 0; i < 4; ++i) {
            int d = d0 + i;
            dst[d * 16 + (((kp >> 2) ^ (d & 3)) << 2) + (kp & 3)] = pack2_rn(pa[i], pb[i]);
        }
    }
}

// LDS: K 8 x 4KB + V 8 x 4KB = 65536 B staging; epilogue overlay (f32):
// m[3][128] + l[3][128] + acc[3][128][33] + ot[2][32][65] = 70400 B.
#define SMEM_BYTES 70400

__global__ __launch_bounds__(512, 4)
void fa_fwd(const float* __restrict__ q, const unsigned short* __restrict__ kws,
            const unsigned short* __restrict__ vws, float* __restrict__ out) {
    __shared__ __align__(16) unsigned char smem[SMEM_BYTES];
    unsigned short* KB = (unsigned short*)smem;           // 8 tiles x 2048 u16
    unsigned short* VB = KB + 16384;                      // 8 tiles x 2048 u16
    float* fb = (float*)smem;

    const int tid = threadIdx.x;
    const int w = tid >> 6, l = tid & 63, h = l >> 5, qr = l & 31;
    const int g = w & 1;          // q-half (also staging role: 0=K, 1=V)
    const int sid = w >> 1;       // k-stream 0..3: k-tiles kidx = 4t+sid
    const int bid = blockIdx.x;
    const int bh = bid & 31;
    const int p = bid >> 5;       // pair index 0..15
    const float QS = 0.18033688011112042f;   // (1/sqrt(64)) * log2(e)

#define STAGE(kidx, buf) do { \
    if (g == 0) { \
        const char* gs_ = (const char*)(kws + (size_t)(bh * 64 + (kidx)) * 2048) + l * 16; \
        char* d_ = (char*)(KB + (sid * 2 + (buf)) * 2048); \
        gl16(gs_, d_); gl16(gs_ + 1024, d_ + 1024); \
        gl16(gs_ + 2048, d_ + 2048); gl16(gs_ + 3072, d_ + 3072); \
    } else { \
        const char* gs_ = (const char*)(vws + (size_t)(bh * 64 + (kidx)) * 2048) + l * 16; \
        char* d_ = (char*)(VB + (sid * 2 + (buf)) * 2048); \
        gl16(gs_, d_); gl16(gs_ + 1024, d_ + 1024); \
        gl16(gs_ + 2048, d_ + 2048); gl16(gs_ + 3072, d_ + 3072); \
    } \
} while (0)

    #pragma unroll 1
    for (int half = 0; half < 2; ++half) {
        const int qt = half ? p : (31 - p);
        const int q0 = qt * QT2;
        const int qbase = q0 + g * 32;
        const int nIter = (qt + 2) >> 1;
        const int kmax = 2 * qt + 1;

        // ---- Q fragments (fp32 load + scale + bf16, once per tile)
        bf16x8 qf[4];
        {
            const float* qp = q + ((size_t)(bh * T_ + qbase + qr)) * D_ + h * 8;
            #pragma unroll
            for (int f = 0; f < 4; ++f) {
                float4 a = *(const float4*)(qp + f * 16);
                float4 b = *(const float4*)(qp + f * 16 + 4);
                u16x8 t;
                t[0] = f2bf_rne(a.x * QS); t[1] = f2bf_rne(a.y * QS);
                t[2] = f2bf_rne(a.z * QS); t[3] = f2bf_rne(a.w * QS);
                t[4] = f2bf_rne(b.x * QS); t[5] = f2bf_rne(b.y * QS);
                t[6] = f2bf_rne(b.z * QS); t[7] = f2bf_rne(b.w * QS);
                qf[f] = __builtin_bit_cast(bf16x8, t);
            }
        }

        f32x16 acc0 = {}, acc1 = {};
        float m = -__builtin_inff(), lsum = 0.f;

        if (sid <= kmax) STAGE(sid, 0);
        __syncthreads();

        int cur = 0;
        for (int t = 0; t < nIter; ++t) {
            const int kbase = (4 * t + sid) * KBLK;
            const int kn = 4 * (t + 1) + sid;
            const bool needN = (t + 1 < nIter) && (kn <= kmax);
            if (needN) STAGE(kn, cur ^ 1);       // async DMA, hidden under compute

            if (kbase <= qbase + 31) {
                const unsigned short* Kt = KB + (sid * 2 + cur) * 2048;
                const unsigned short* Vt = VB + (sid * 2 + cur) * 2048;
                // ---- S^T = K_tile . Q^T (swizzled K reads)
                f32x16 sv = {};
                __builtin_amdgcn_s_setprio(1);
                #pragma unroll
                for (int f = 0; f < 4; ++f) {
                    bf16x8 aK = *(const bf16x8*)(Kt + qr * 64 + (((f * 2 + h) ^ (qr & 7)) << 3));
                    sv = __builtin_amdgcn_mfma_f32_32x32x16_bf16(aK, qf[f], sv, 0, 0, 0);
                }
                __builtin_amdgcn_s_setprio(0);
                if (kbase == qbase) {            // diagonal: causal mask
                    #pragma unroll
                    for (int r = 0; r < 16; ++r) {
                        int kc = (r & 3) + ((r >> 2) << 3) + (h << 2);
                        if (kc > qr) sv[r] = -1e9f;
                    }
                }
                // ---- online softmax, tree reduce, defer-max rescale (T13)
                float pm = fmaxf(
                    fmaxf(fmaxf(fmaxf(sv[0], sv[1]), fmaxf(sv[2], sv[3])),
                          fmaxf(fmaxf(sv[4], sv[5]), fmaxf(sv[6], sv[7]))),
                    fmaxf(fmaxf(fmaxf(sv[8], sv[9]), fmaxf(sv[10], sv[11])),
                          fmaxf(fmaxf(sv[12], sv[13]), fmaxf(sv[14], sv[15]))));
                pm = fmaxf(pm, xhalf(pm));
                if (__any(pm > m + 8.0f)) {      // rescale only when needed
                    float mnew = fmaxf(m, pm);
                    float corr = exp2fast(m - mnew);
                    m = mnew;
                    lsum *= corr;
                    acc0 *= corr; acc1 *= corr;
                }
                #pragma unroll
                for (int r = 0; r < 16; ++r) sv[r] = exp2fast(sv[r] - m);
                float ps =
                    (((sv[0] + sv[1]) + (sv[2] + sv[3])) + ((sv[4] + sv[5]) + (sv[6] + sv[7]))) +
                    (((sv[8] + sv[9]) + (sv[10] + sv[11])) + ((sv[12] + sv[13]) + (sv[14] + sv[15])));
                ps += xhalf(ps);
                lsum += ps;
                // ---- P -> bf16 PV fragments
                unsigned w00 = pack2_rn(sv[0],  sv[1]),  w01 = pack2_rn(sv[2],  sv[3]);
                unsigned w10 = pack2_rn(sv[4],  sv[5]),  w11 = pack2_rn(sv[6],  sv[7]);
                unsigned w20 = pack2_rn(sv[8],  sv[9]),  w21 = pack2_rn(sv[10], sv[11]);
                unsigned w30 = pack2_rn(sv[12], sv[13]), w31 = pack2_rn(sv[14], sv[15]);
                swapu(w00, w10); swapu(w01, w11); swapu(w20, w30); swapu(w21, w31);
                u32x4 f0v = { w00, w01, w10, w11 };
                u32x4 f1v = { w20, w21, w30, w31 };
                bf16x8 bp0 = __builtin_bit_cast(bf16x8, f0v);
                bf16x8 bp1 = __builtin_bit_cast(bf16x8, f1v);
                // ---- O^T += V^T . P^T (swizzled V^T reads)
                __builtin_amdgcn_s_setprio(1);
                bf16x8 aV;
                aV = *(const bf16x8*)(Vt + qr * 32 + ((h ^ (qr & 3)) << 3));
                acc0 = __builtin_amdgcn_mfma_f32_32x32x16_bf16(aV, bp0, acc0, 0, 0, 0);
                aV = *(const bf16x8*)(Vt + qr * 32 + (((2 + h) ^ (qr & 3)) << 3));
                acc0 = __builtin_amdgcn_mfma_f32_32x32x16_bf16(aV, bp1, acc0, 0, 0, 0);
                aV = *(const bf16x8*)(Vt + (32 + qr) * 32 + ((h ^ (qr & 3)) << 3));
                acc1 = __builtin_amdgcn_mfma_f32_32x32x16_bf16(aV, bp0, acc1, 0, 0, 0);
                aV = *(const bf16x8*)(Vt + (32 + qr) * 32 + (((2 + h) ^ (qr & 3)) << 3));
                acc1 = __builtin_amdgcn_mfma_f32_32x32x16_bf16(aV, bp1, acc1, 0, 0, 0);
                __builtin_amdgcn_s_setprio(0);
            }
            __syncthreads();                     // also drains this iter's DMA
            cur ^= 1;
        }

        // ---- epilogue: 4-stream merge, transpose, coalesced store
        float* mbuf = fb;                    // [3][128]
        float* lbuf = fb + 384;              // [3][128]
        float* abuf = fb + 768;              // [3][128][33]
        float* ot   = fb + 13440;            // [2][32][65]
        const int row = g * 64 + l;
        if (sid != 0) {
            const int ps2 = sid - 1;
            mbuf[ps2 * 128 + row] = m;
            lbuf[ps2 * 128 + row] = lsum;
            float* ap = abuf + (ps2 * 128 + row) * 33;
            #pragma unroll
            for (int r = 0; r < 16; ++r) { ap[r] = acc0[r]; ap[16 + r] = acc1[r]; }
        }
        __syncthreads();
        if (sid == 0) {
            float m1 = mbuf[row], m2 = mbuf[128 + row], m3 = mbuf[256 + row];
            float ms = fmaxf(fmaxf(m, m1), fmaxf(m2, m3));
            float c0 = exp2fast(m - ms),  c1 = exp2fast(m1 - ms);
            float c2 = exp2fast(m2 - ms), c3 = exp2fast(m3 - ms);
            float lt = lsum * c0 + lbuf[row] * c1 + lbuf[128 + row] * c2 + lbuf[256 + row] * c3;
            float inv = 1.0f / lt;
            const float* a1 = abuf + row * 33;
            const float* a2 = abuf + (128 + row) * 33;
            const float* a3 = abuf + (256 + row) * 33;
            float* og = ot + g * 2080;
            #pragma unroll
            for (int r = 0; r < 16; ++r) {
                int d = (r & 3) + ((r >> 2) << 3) + (h << 2);
                og[qr * 65 + d] =
                    (acc0[r] * c0 + a1[r] * c1 + a2[r] * c2 + a3[r] * c3) * inv;
                og[qr * 65 + 32 + d] =
                    (acc1[r] * c0 + a1[16 + r] * c1 + a2[16 + r] * c2 + a3[16 + r] * c3) * inv;
            }
        }
        __syncthreads();
        float* ob = out + (size_t)(bh * T_ + q0) * D_;
        #pragma unroll
        for (int i = 0; i < 2; ++i) {
            int idx = i * 512 + tid;
            int r2 = idx >> 4, c4 = (idx & 15) << 2;
            const float* src = ot + (r2 >> 5) * 2080 + (r2 & 31) * 65 + c4;
            float4 val; val.x = src[0]; val.y = src[1]; val.z = src[2]; val.w = src[3];
            *(float4*)(ob + r2 * D_ + c4) = val;
        }
        __syncthreads();                     // ot read done before next half stages
    }
#undef STAGE
}

extern "C" void kernel_launch(void* const* d_in, const int* in_sizes, int n_in,
                              void* d_out, int out_size, void* d_ws, size_t ws_size,
                              hipStream_t stream) {
    const float* q = (const float*)d_in[0];
    const float* k = (const float*)d_in[1];
    const float* v = (const float*)d_in[2];
    float* out = (float*)d_out;
    unsigned short* kws = (unsigned short*)d_ws;            // 8,388,608 B
    unsigned short* vws = kws + 4194304;                    // 8,388,608 B
    prep<<<dim3(4096), dim3(256), 0, stream>>>(k, v, kws, vws);
    fa_fwd<<<dim3(BH_ * 16), dim3(512), 0, stream>>>(q, kws, vws, out);
}